// Round 5
// baseline (33.246 us; speedup 1.0000x reference)
//
#include <hip/hip_runtime.h>

#define NC   80
#define CCH  85
#define NBATCH 32

#define HW0 6400
#define HW1 1600
#define HW2 400
#define NCELL0 (NBATCH*HW0)   // 204800
#define NCELL1 (NBATCH*HW1)   // 51200
#define NCELL2 (NBATCH*HW2)   // 12800
#define NCELL_TOT (NCELL0+NCELL1+NCELL2)  // 268800
#define BMWORDS ((NCELL_TOT+31)/32)       // 8400 words = 33.6KB LDS bitmap

#define MAXSLOTS 1024

static __device__ __forceinline__ float softplus_ref(float x) {
    return fmaxf(x, 0.f) + log1pf(expf(-fabsf(x)));
}

template <int HW, int NCELLS>
static __device__ __forceinline__ void obj_scale_loop(
        const float* __restrict__ pred, float& acc, int gtid, int gstride) {
    const int NG = NCELLS / 4;
    const float inv_norm = 1.f / (float)NCELLS;
    for (int g = gtid; g < NG; g += gstride) {
        int cell = g * 4;
        int b    = cell / HW;
        int pos  = cell - b * HW;
        const float4 x4 = *reinterpret_cast<const float4*>(
            pred + (size_t)b * CCH * HW + (size_t)4 * HW + pos);
        acc += (softplus_ref(x4.x) + softplus_ref(x4.y)
              + softplus_ref(x4.z) + softplus_ref(x4.w)) * inv_norm;
    }
}

static __device__ __forceinline__ float block_reduce(float v, float* red, int tid) {
    red[tid] = v; __syncthreads();
    #pragma unroll
    for (int off = 128; off > 0; off >>= 1) {
        if (tid < off) red[tid] += red[tid + off];
        __syncthreads();
    }
    float r = red[0]; __syncthreads();
    return r;
}

__global__ __launch_bounds__(256)
void k_fused(const float* __restrict__ p0, const float* __restrict__ p1,
             const float* __restrict__ p2, const float* __restrict__ tgt,
             int n, int nb, float inv_n,
             float* __restrict__ box_part, float* __restrict__ cls_part,
             float* __restrict__ objd_part, float* __restrict__ corr_slot,
             unsigned int* __restrict__ counter, float* __restrict__ out) {
    __shared__ unsigned int bitmap[BMWORDS];
    __shared__ float red[256];
    __shared__ int islast;
    const int tid = threadIdx.x;
    const int bid = blockIdx.x;

    // ---- phase 1: dense softplus over the 3 objectness planes ----
    float objd = 0.f;
    {
        int gtid = bid * 256 + tid, gstride = nb * 256;
        obj_scale_loop<HW0, NCELL0>(p0, objd, gtid, gstride);
        obj_scale_loop<HW1, NCELL1>(p1, objd, gtid, gstride);
        obj_scale_loop<HW2, NCELL2>(p2, objd, gtid, gstride);
    }

    // ---- phase 2: per-target box + cls (16 lanes per target) ----
    float cls_sum = 0.f, box_sum = 0.f;
    {
        int gid = bid * 256 + tid;
        int t = gid >> 4, lane = gid & 15;
        if (t < n) {
            const float* tr = tgt + (size_t)t * 6;
            int   b   = (int)tr[0];
            int   cls = (int)tr[1];
            float cx = tr[2], cy = tr[3], bw = tr[4], bh = tr[5];
            float area = fmaxf(bw * bh, 1e-6f);
            int s = (area <= 0.01f) ? 0 : ((area <= 0.03f) ? 1 : 2);
            int w = 80 >> s, hw = w * w;
            const float* pred = (s == 0) ? p0 : ((s == 1) ? p1 : p2);
            int gx = (int)(cx * (float)w); gx = min(max(gx, 0), w - 1);
            int gy = (int)(cy * (float)w); gy = min(max(gy, 0), w - 1);
            const float* base = pred + (size_t)b * CCH * hw + (size_t)gy * w + gx;

            #pragma unroll
            for (int k = 0; k < 5; k++) {
                int c = lane * 5 + k;
                float x  = base[(size_t)(5 + c) * hw];
                float tv = (c == cls) ? 1.f : 0.f;
                cls_sum += fmaxf(x, 0.f) - x * tv + log1pf(expf(-fabsf(x)));
            }
            cls_sum *= (1.f / (float)NC);

            if (lane == 0) {
                float pv0 = base[0];
                float pv1 = base[(size_t)hw];
                float pv2 = base[(size_t)2 * hw];
                float pv3 = base[(size_t)3 * hw];
                float px = (1.f / (1.f + expf(-pv0)) + (float)gx) / (float)w;
                float py = (1.f / (1.f + expf(-pv1)) + (float)gy) / (float)w;
                float pw = expf(fminf(pv2, 4.f)) / (float)w;
                float ph = expf(fminf(pv3, 4.f)) / (float)w;
                float l1 = (fabsf(px - cx) + fabsf(py - cy) + fabsf(pw - bw) + fabsf(ph - bh)) * 0.25f;
                float weight = 1.f + 2.f * (1.f - sqrtf(area));
                box_sum = l1 * weight;
            }
        }
    }

    // ---- phase 3: dedup'd obj correction (single block 0) ----
    float corr = 0.f;
    if (bid == 0) {
        for (int i = tid; i < BMWORDS; i += 256) bitmap[i] = 0u;
        __syncthreads();
        for (int t = tid; t < n; t += 256) {
            const float* tr = tgt + (size_t)t * 6;
            int   b  = (int)tr[0];
            float cx = tr[2], cy = tr[3], bw = tr[4], bh = tr[5];
            float area = fmaxf(bw * bh, 1e-6f);
            int s = (area <= 0.01f) ? 0 : ((area <= 0.03f) ? 1 : 2);
            int w = 80 >> s, hw = w * w;
            const float* pred = (s == 0) ? p0 : ((s == 1) ? p1 : p2);
            float invn = (s == 0) ? (1.f / (float)NCELL0)
                       : ((s == 1) ? (1.f / (float)NCELL1) : (1.f / (float)NCELL2));
            int gx = (int)(cx * (float)w); gx = min(max(gx, 0), w - 1);
            int gy = (int)(cy * (float)w); gy = min(max(gy, 0), w - 1);
            int cellbase = (s == 0) ? 0 : ((s == 1) ? NCELL0 : (NCELL0 + NCELL1));
            int cell = cellbase + b * hw + gy * w + gx;
            unsigned int bit = 1u << (cell & 31);
            unsigned int old = atomicOr(&bitmap[cell >> 5], bit);
            if (!(old & bit)) {
                float x = pred[(size_t)b * CCH * hw + (size_t)4 * hw + (size_t)gy * w + gx];
                corr += x * invn;   // value depends only on cell -> deterministic
            }
        }
        __syncthreads();
    }

    // ---- per-block reductions -> own slot, via device-scope atomic RMW ----
    float c = block_reduce(cls_sum, red, tid);
    if (tid == 0) atomicExch(&cls_part[bid], c);
    float bx = block_reduce(box_sum, red, tid);
    if (tid == 0) atomicExch(&box_part[bid], bx);
    float od = block_reduce(objd, red, tid);
    if (tid == 0) atomicExch(&objd_part[bid], od);
    if (bid == 0) {
        float cr = block_reduce(corr, red, tid);
        if (tid == 0) atomicExch(corr_slot, cr);
    }

    // ---- last-arrival finalize (counter reset to 0 by host-side memset) ----
    __threadfence();
    if (tid == 0) {
        unsigned int prev = atomicAdd(counter, 1u);
        islast = (prev == (unsigned)(nb - 1)) ? 1 : 0;
    }
    __syncthreads();
    if (islast) {
        __threadfence();
        float bs = 0.f, cs = 0.f, os = 0.f;
        for (int i = tid; i < nb; i += 256) {
            bs += atomicAdd(&box_part[i], 0.f);    // coherent device-scope read
            cs += atomicAdd(&cls_part[i], 0.f);
            os += atomicAdd(&objd_part[i], 0.f);
        }
        bs = block_reduce(bs, red, tid);
        cs = block_reduce(cs, red, tid);
        os = block_reduce(os, red, tid);
        if (tid == 0) {
            float crs = atomicAdd(corr_slot, 0.f);
            float box = bs * inv_n;
            float cls = cs * inv_n;
            float obj = os - crs;
            out[0] = box + obj + cls;
            out[1] = box;
            out[2] = obj;
            out[3] = cls;
        }
    }
}

extern "C" void kernel_launch(void* const* d_in, const int* in_sizes, int n_in,
                              void* d_out, int out_size, void* d_ws, size_t ws_size,
                              hipStream_t stream) {
    const float* p0  = (const float*)d_in[0];
    const float* p1  = (const float*)d_in[1];
    const float* p2  = (const float*)d_in[2];
    const float* tgt = (const float*)d_in[3];
    int n = in_sizes[3] / 6;

    char* ws = (char*)d_ws;
    float*        box_part  = (float*)ws;
    float*        cls_part  = (float*)(ws + MAXSLOTS * 4);
    float*        objd_part = (float*)(ws + 2 * MAXSLOTS * 4);
    float*        corr_slot = (float*)(ws + 3 * MAXSLOTS * 4);
    unsigned int* counter   = (unsigned int*)(ws + 3 * MAXSLOTS * 4 + 64);

    int need = (n * 16 + 255) / 256;
    int nb = 64;
    while (nb < need && nb < MAXSLOTS) nb <<= 1;     // n=2048 -> 128

    float inv_n = 1.f / (float)((n > 1) ? n : 1);

    // Reset the arrival counter to a known 0 every call (graph-capturable).
    hipMemsetAsync(counter, 0, 4, stream);

    k_fused<<<nb, 256, 0, stream>>>(p0, p1, p2, tgt, n, nb, inv_n,
                                    box_part, cls_part, objd_part, corr_slot,
                                    counter, (float*)d_out);
}